// Round 5
// baseline (363.498 us; speedup 1.0000x reference)
//
#include <hip/hip_runtime.h>

typedef short short8 __attribute__((ext_vector_type(8)));
typedef float floatx4 __attribute__((ext_vector_type(4)));

__device__ __forceinline__ unsigned short f2bf(float f) {
  unsigned int u = __float_as_uint(f);
  u += 0x7FFFu + ((u >> 16) & 1u);   // RNE
  return (unsigned short)(u >> 16);
}

#if __has_builtin(__builtin_amdgcn_cvt_pk_bf16_f32)
typedef __bf16 bf16x2_t __attribute__((ext_vector_type(2)));
__device__ __forceinline__ unsigned int pk2bf(float lo, float hi) {
  bf16x2_t v = __builtin_amdgcn_cvt_pk_bf16_f32(lo, hi);
  return __builtin_bit_cast(unsigned int, v);
}
#else
__device__ __forceinline__ unsigned int pk2bf(float lo, float hi) {
  return (unsigned)f2bf(lo) | ((unsigned)f2bf(hi) << 16);
}
#endif

// ---------------------------------------------------------------------------
// Fused setup: job0 zero d_out | job1 zero hist | job2 x->bf16 | job3 weight
// repack (fragment layout per R1; biases folded as K-row 129).
// Jobs are independent buffers -> safe to run concurrently in one dispatch.
// ---------------------------------------------------------------------------
__global__ __launch_bounds__(256) void k_setup(
    float* __restrict__ out, int out_n,
    int* __restrict__ hist, int N,
    const float* __restrict__ x, unsigned short* __restrict__ xb, int nx,
    const float* __restrict__ W1x, const float* __restrict__ W1p,
    const float* __restrict__ b1x, const float* __restrict__ b1p,
    const float* __restrict__ W2x, unsigned short* __restrict__ wbuf,
    int b1, int b2, int b3)   // job boundaries (block ids)
{
  int blk = blockIdx.x, t = threadIdx.x;
  if (blk < b1) {                                   // job0: zero d_out
    int i = (blk * 256 + t) * 4;
    if (i + 4 <= out_n) {
      *(float4*)(out + i) = make_float4(0.f, 0.f, 0.f, 0.f);
    } else {
      for (int k = i; k < out_n; ++k) out[k] = 0.f;
    }
  } else if (blk < b2) {                            // job1: zero hist
    int i = (blk - b1) * 256 + t;
    if (i < N) hist[i] = 0;
  } else if (blk < b3) {                            // job2: x -> bf16
    int i = ((blk - b2) * 256 + t) * 8;
    if (i < nx) {
      float4 a = *(const float4*)(x + i);
      float4 b = *(const float4*)(x + i + 4);
      uint4 o;
      o.x = pk2bf(a.x, a.y); o.y = pk2bf(a.z, a.w);
      o.z = pk2bf(b.x, b.y); o.w = pk2bf(b.z, b.w);
      *(uint4*)(xb + i) = o;
    }
  } else {                                          // job3: weight repack
    int i = (blk - b3) * 256 + t;
    if (i >= 49152) return;
    float v;
    if (i < 40960) {
      const float* W = (i < 20480) ? W1x : W1p;
      const float* B = (i < 20480) ? b1x : b1p;
      int j = (i < 20480) ? i : i - 20480;
      int jj   = j & 7;
      int lane = (j >> 3) & 63;
      int ks   = (j >> 9) % 5;
      int nt   = j / 2560;
      int k = ks*32 + (lane >> 4)*8 + jj;
      int n = nt*16 + (lane & 15);
      v = (k < 129) ? W[k*128 + n] : (k == 129 ? B[n] : 0.0f);
    } else {
      int j = i - 40960;
      int jj   = j & 7;
      int lane = (j >> 3) & 63;
      int ks   = (j >> 9) & 3;
      int nt   = j >> 11;
      int k = ks*32 + (lane >> 4)*8 + jj;
      int n = nt*16 + (lane & 15);
      v = W2x[k*64 + n];
    }
    wbuf[i] = f2bf(v);
  }
}

// ---------------------------------------------------------------------------
// Counting sort by destination (col): hist -> scan -> scatter.
// ---------------------------------------------------------------------------
__global__ void k_hist(const int* __restrict__ col, int E, int* __restrict__ hist) {
  int i = blockIdx.x * 256 + threadIdx.x;
  if (i < E) atomicAdd(&hist[col[i]], 1);
}

__global__ __launch_bounds__(256) void k_scan_a(const int* __restrict__ hist, int N,
                                                int* __restrict__ excl, int* __restrict__ bsum) {
  __shared__ int wtot[4], wexc[4];
  int t = threadIdx.x, lane = t & 63, w = t >> 6;
  int base = blockIdx.x * 1024 + t * 4;
  int v0 = (base + 0 < N) ? hist[base + 0] : 0;
  int v1 = (base + 1 < N) ? hist[base + 1] : 0;
  int v2 = (base + 2 < N) ? hist[base + 2] : 0;
  int v3 = (base + 3 < N) ? hist[base + 3] : 0;
  int T = v0 + v1 + v2 + v3;
  int inc = T;
  #pragma unroll
  for (int s = 1; s < 64; s <<= 1) {
    int u = __shfl_up(inc, s, 64);
    if (lane >= s) inc += u;
  }
  if (lane == 63) wtot[w] = inc;
  __syncthreads();
  if (t == 0) {
    int a = 0;
    #pragma unroll
    for (int i = 0; i < 4; ++i) { wexc[i] = a; a += wtot[i]; }
    bsum[blockIdx.x] = a;
  }
  __syncthreads();
  int tex = wexc[w] + (inc - T);
  if (base + 0 < N) excl[base + 0] = tex;
  if (base + 1 < N) excl[base + 1] = tex + v0;
  if (base + 2 < N) excl[base + 2] = tex + v0 + v1;
  if (base + 3 < N) excl[base + 3] = tex + v0 + v1 + v2;
}

// scatter with inlined top-level scan of per-scan_a-block sums (NB <= 64)
__global__ __launch_bounds__(256) void k_scatter(
    const int* __restrict__ row, const int* __restrict__ col, int E,
    int* __restrict__ excl, const int* __restrict__ bsum, int NB,
    int2* __restrict__ sedge) {
  __shared__ int boff_sh[64];
  int t = threadIdx.x;
  if (t < 64) {
    int v = (t < NB) ? bsum[t] : 0;
    int inc = v;
    #pragma unroll
    for (int s = 1; s < 64; s <<= 1) {
      int u = __shfl_up(inc, s, 64);
      if (t >= s) inc += u;
    }
    boff_sh[t] = inc - v;
  }
  __syncthreads();
  int i = blockIdx.x * 256 + t;
  if (i < E) {
    int c = col[i];
    int p = atomicAdd(&excl[c], 1) + boff_sh[c >> 10];
    sedge[p] = make_int2(row[i], c);
  }
}

// ---------------------------------------------------------------------------
// Main fused kernel: 64 sorted edges/block, 256 threads.
// Transposed GEMMs, persistent weight A-fragments; biases via K-row 129.
// H^T overlays C_lds (rows [et*16,et*16+16) are dead after GEMM1 iter et;
// per-et barrier guards the overwrite) -> LDS 23.5 KB -> 6 blocks/CU.
// XCD swizzle: contiguous sorted-edge blocks land on one XCD for atomic
// L2 locality. Segmented suffix-sum epilogue over sorted cols (R2).
// ---------------------------------------------------------------------------
__global__ __launch_bounds__(256) void mp_main(
    const float* __restrict__ x, const unsigned short* __restrict__ xb, int use_xb,
    const float* __restrict__ pos,
    const int2* __restrict__ sedge,
    const int* __restrict__ rowp, const int* __restrict__ colp,
    int E, int sorted, int chunk,
    const float* __restrict__ b2x, const float* __restrict__ W2p,
    const float* __restrict__ b2p,
    const unsigned short* __restrict__ wbuf,
    float* __restrict__ out_x, float* __restrict__ out_pos)
{
  __shared__ __align__(16) unsigned short C_lds[64][168];  // 21504 B
  __shared__ float rel_lds[64][3];
  __shared__ int   col_sh[64];
  __shared__ float wsum[4][64];

  // XCD-contiguous remap: blocks with the same (bid & 7) form one contiguous
  // edge range; HW round-robins bid%8 across XCDs.
  const int nblk = (E + 63) >> 6;
  const int logical = (blockIdx.x & 7) * chunk + (blockIdx.x >> 3);
  if (logical >= nblk) return;            // uniform exit, before any barrier
  const int e0 = logical * 64;

  const int t    = threadIdx.x;
  const int wv   = t >> 6;
  const int lane = t & 63;
  const int quad = lane >> 4;
  const int lc   = lane & 15;

  // ---- persistent weight fragments (issue early; no LDS dependence) ----
  const short8* __restrict__ w1x_f = (const short8*)(wbuf);
  const short8* __restrict__ w1p_f = (const short8*)(wbuf + 20480);
  const short8* __restrict__ w2x_f = (const short8*)(wbuf + 40960);

  short8 a1x[2][5], a1p[2][5], a2w[4];
  #pragma unroll
  for (int i = 0; i < 2; ++i) {
    int hti = wv + 4*i;
    #pragma unroll
    for (int ks = 0; ks < 5; ++ks) {
      a1x[i][ks] = w1x_f[(hti*5 + ks)*64 + lane];
      a1p[i][ks] = w1p_f[(hti*5 + ks)*64 + lane];
    }
  }
  #pragma unroll
  for (int ks = 0; ks < 4; ++ks) a2w[ks] = w2x_f[(wv*4 + ks)*64 + lane];

  float wp2[2][4], b2xr[4];
  #pragma unroll
  for (int i = 0; i < 2; ++i)
    #pragma unroll
    for (int r = 0; r < 4; ++r) wp2[i][r] = W2p[(wv + 4*i)*16 + quad*4 + r];
  #pragma unroll
  for (int r = 0; r < 4; ++r) b2xr[r] = b2x[wv*16 + quad*4 + r];
  const float b2ps = b2p[0];

  // ---- phase 1: per-edge scalars + combined-feature staging (bf16) ----
  if (t < 64) {
    int e = e0 + t;
    float rp0 = 0.f, rp1 = 0.f, rp2 = 0.f, dsq = 0.f; int c = -1;
    if (e < E) {
      int r;
      if (sorted) { int2 rc = sedge[e]; r = rc.x; c = rc.y; }
      else        { r = rowp[e]; c = colp[e]; }
      float pr0 = pos[r*3+0], pr1 = pos[r*3+1], pr2 = pos[r*3+2];
      float pc0 = pos[c*3+0], pc1 = pos[c*3+1], pc2 = pos[c*3+2];
      rp0 = pr0 - pc0; rp1 = pr1 - pc1; rp2 = pr2 - pc2;
      dsq = rp0*rp0 + rp1*rp1 + rp2*rp2;
    }
    rel_lds[t][0] = rp0; rel_lds[t][1] = rp1; rel_lds[t][2] = rp2;
    col_sh[t] = c;
    C_lds[t][128] = f2bf(dsq);
    C_lds[t][129] = 0x3F80;            // 1.0 -> multiplies folded bias row
    #pragma unroll
    for (int k = 130; k < 160; ++k) C_lds[t][k] = 0;
  }
  {
    const int s = t >> 2, p = t & 3;     // 4 threads/edge, 16 feats each side
    const int e = e0 + s;
    uint4 r0, r1, c0, c1;
    if (e < E) {
      int r, c;
      if (sorted) { int2 rc = sedge[e]; r = rc.x; c = rc.y; }
      else        { r = rowp[e]; c = colp[e]; }
      if (use_xb) {
        const uint4* xr = (const uint4*)(xb + (size_t)r*64 + p*16);
        const uint4* xc = (const uint4*)(xb + (size_t)c*64 + p*16);
        r0 = xr[0]; r1 = xr[1];
        c0 = xc[0]; c1 = xc[1];
      } else {
        const float4* xr = (const float4*)(x + (size_t)r*64 + p*16);
        const float4* xc = (const float4*)(x + (size_t)c*64 + p*16);
        float4 a0 = xr[0], a1 = xr[1], a2 = xr[2], a3 = xr[3];
        float4 d0 = xc[0], d1 = xc[1], d2 = xc[2], d3 = xc[3];
        r0 = make_uint4(pk2bf(a0.x,a0.y), pk2bf(a0.z,a0.w), pk2bf(a1.x,a1.y), pk2bf(a1.z,a1.w));
        r1 = make_uint4(pk2bf(a2.x,a2.y), pk2bf(a2.z,a2.w), pk2bf(a3.x,a3.y), pk2bf(a3.z,a3.w));
        c0 = make_uint4(pk2bf(d0.x,d0.y), pk2bf(d0.z,d0.w), pk2bf(d1.x,d1.y), pk2bf(d1.z,d1.w));
        c1 = make_uint4(pk2bf(d2.x,d2.y), pk2bf(d2.z,d2.w), pk2bf(d3.x,d3.y), pk2bf(d3.z,d3.w));
      }
    } else {
      r0 = r1 = c0 = c1 = make_uint4(0u, 0u, 0u, 0u);
    }
    uint4* dr = (uint4*)&C_lds[s][p*16];
    dr[0] = r0; dr[1] = r1;
    uint4* dc = (uint4*)&C_lds[s][64 + p*16];
    dc[0] = c0; dc[1] = c1;
  }
  __syncthreads();

  // ---- GEMM1 (x & p fused), silu; H^T overlays C_lds rows of this et ----
  #pragma unroll 1
  for (int et = 0; et < 4; ++et) {
    floatx4 ax0 = {0,0,0,0}, ax1 = {0,0,0,0}, ap0 = {0,0,0,0}, ap1 = {0,0,0,0};
    #pragma unroll
    for (int ks = 0; ks < 5; ++ks) {
      short8 b = *(const short8*)&C_lds[et*16 + lc][ks*32 + quad*8];
      ax0 = __builtin_amdgcn_mfma_f32_16x16x32_bf16(a1x[0][ks], b, ax0, 0, 0, 0);
      ax1 = __builtin_amdgcn_mfma_f32_16x16x32_bf16(a1x[1][ks], b, ax1, 0, 0, 0);
      ap0 = __builtin_amdgcn_mfma_f32_16x16x32_bf16(a1p[0][ks], b, ap0, 0, 0, 0);
      ap1 = __builtin_amdgcn_mfma_f32_16x16x32_bf16(a1p[1][ks], b, ap1, 0, 0, 0);
    }
    float ps = 0.f;
    uint2 hw[2];
    #pragma unroll
    for (int i = 0; i < 2; ++i) {
      floatx4 axx = i ? ax1 : ax0;
      floatx4 app = i ? ap1 : ap0;
      float sx[4];
      #pragma unroll
      for (int r = 0; r < 4; ++r) {
        float h  = axx[r];                                 // bias already in
        sx[r] = h * __builtin_amdgcn_rcpf(1.f + __expf(-h));
        float hp = app[r];
        float sp = hp * __builtin_amdgcn_rcpf(1.f + __expf(-hp));
        ps += sp * wp2[i][r];
      }
      hw[i] = make_uint2(pk2bf(sx[0], sx[1]), pk2bf(sx[2], sx[3]));
    }
    __syncthreads();   // all waves done reading C rows [et*16, et*16+16)
    #pragma unroll
    for (int i = 0; i < 2; ++i)
      *(uint2*)&C_lds[et*16 + lc][(wv + 4*i)*16 + quad*4] = hw[i];
    ps += __shfl_xor(ps, 16, 64);
    ps += __shfl_xor(ps, 32, 64);
    if (lane < 16) wsum[wv][et*16 + lane] = ps;
  }
  __syncthreads();

  // ---- GEMM2: MSG^T = W2x^T @ H^T (from C_lds), segmented scatter ----
  #pragma unroll 2
  for (int et = 0; et < 4; ++et) {
    floatx4 acc = {0,0,0,0};
    #pragma unroll
    for (int ks = 0; ks < 4; ++ks) {
      short8 b = *(const short8*)&C_lds[et*16 + lc][ks*32 + quad*8];
      acc = __builtin_amdgcn_mfma_f32_16x16x32_bf16(a2w[ks], b, acc, 0, 0, 0);
    }
    int edge = et*16 + lc;
    int myc = col_sh[edge];
    float v0 = acc[0] + b2xr[0], v1 = acc[1] + b2xr[1];
    float v2 = acc[2] + b2xr[2], v3 = acc[3] + b2xr[3];
    if (sorted) {
      #pragma unroll
      for (int s = 1; s < 16; s <<= 1) {
        int   nc  = __shfl_down(myc, s, 64);
        float n0  = __shfl_down(v0,  s, 64);
        float n1  = __shfl_down(v1,  s, 64);
        float n2  = __shfl_down(v2,  s, 64);
        float n3  = __shfl_down(v3,  s, 64);
        if ((lc + s < 16) && (nc == myc)) { v0 += n0; v1 += n1; v2 += n2; v3 += n3; }
      }
    }
    bool head = (myc >= 0) && (!sorted || lc == 0 || col_sh[edge-1] != myc);
    if (head) {
      float* dst = out_x + (size_t)myc*64 + wv*16 + quad*4;
      atomicAdd(dst + 0, v0);
      atomicAdd(dst + 1, v1);
      atomicAdd(dst + 2, v2);
      atomicAdd(dst + 3, v3);
    }
  }

  // ---- phi_p epilogue: weight * rel_pos, segmented over 64 sorted edges ----
  if (t < 64) {
    int c = col_sh[t];
    float w = wsum[0][t] + wsum[1][t] + wsum[2][t] + wsum[3][t] + b2ps;
    float p0 = w * rel_lds[t][0], p1 = w * rel_lds[t][1], p2 = w * rel_lds[t][2];
    if (sorted) {
      #pragma unroll
      for (int s = 1; s < 64; s <<= 1) {
        int   nc = __shfl_down(c,  s, 64);
        float n0 = __shfl_down(p0, s, 64);
        float n1 = __shfl_down(p1, s, 64);
        float n2 = __shfl_down(p2, s, 64);
        if ((t + s < 64) && (nc == c)) { p0 += n0; p1 += n1; p2 += n2; }
      }
    }
    bool head = (c >= 0) && (!sorted || t == 0 || col_sh[t-1] != c);
    if (head) {
      atomicAdd(&out_pos[(size_t)c*3 + 0], p0);
      atomicAdd(&out_pos[(size_t)c*3 + 1], p1);
      atomicAdd(&out_pos[(size_t)c*3 + 2], p2);
    }
  }
}

extern "C" void kernel_launch(void* const* d_in, const int* in_sizes, int n_in,
                              void* d_out, int out_size, void* d_ws, size_t ws_size,
                              hipStream_t stream) {
  const float* x   = (const float*)d_in[0];
  const float* pos = (const float*)d_in[1];
  const int*   ei  = (const int*)d_in[2];
  const float* W1x = (const float*)d_in[3];
  const float* b1x = (const float*)d_in[4];
  const float* W2x = (const float*)d_in[5];
  const float* b2x = (const float*)d_in[6];
  const float* W1p = (const float*)d_in[7];
  const float* b1p = (const float*)d_in[8];
  const float* W2p = (const float*)d_in[9];
  const float* b2p = (const float*)d_in[10];

  const int E = in_sizes[2] / 2;        // 800000
  const int N = in_sizes[0] / 64;       // 50000
  const int* rowp = ei;
  const int* colp = ei + E;
  float* out_x   = (float*)d_out;
  float* out_pos = out_x + (size_t)N * 64;

  char* ws = (char*)d_ws;
  const size_t xb_bytes = (size_t)N * 64 * 2;        // 6,400,000
  size_t base = 0;
  int use_xb = 0;
  {
    size_t needA = xb_bytes + 98304 + 200192 + 512 + (size_t)E * 8;
    if (ws_size >= needA) { use_xb = 1; base = xb_bytes; }
  }
  unsigned short* xb   = (unsigned short*)ws;
  unsigned short* wbuf = (unsigned short*)(ws + base);
  int*  off   = (int*)(ws + base + 98304);
  int*  bsum  = (int*)(ws + base + 98304 + 200192);
  int2* sedge = (int2*)(ws + base + 98304 + 200192 + 512);
  const size_t need_sort = base + 98304 + 200192 + 512 + (size_t)E * 8;
  const int use_sort = (ws_size >= need_sort) ? 1 : 0;

  // fused setup dispatch
  const int nx = N * 64;
  const int nb_out  = (out_size + 1023) / 1024;          // 4 floats/thread
  const int nb_hist = use_sort ? (N + 255) / 256 : 0;
  const int nb_xcvt = use_xb ? (nx + 2047) / 2048 : 0;   // 8 elems/thread
  const int nb_prep = 192;
  const int b1 = nb_out, b2 = b1 + nb_hist, b3 = b2 + nb_xcvt;
  const int setup_blocks = b3 + nb_prep;
  k_setup<<<setup_blocks, 256, 0, stream>>>(
      (float*)d_out, out_size, off, N, x, xb, nx,
      W1x, W1p, b1x, b1p, W2x, wbuf, b1, b2, b3);

  if (use_sort) {
    const int NB = (N + 1023) / 1024;   // 49 (<=64)
    k_hist<<<(E + 255) / 256, 256, 0, stream>>>(colp, E, off);
    k_scan_a<<<NB, 256, 0, stream>>>(off, N, off, bsum);
    k_scatter<<<(E + 255) / 256, 256, 0, stream>>>(rowp, colp, E, off, bsum, NB, sedge);
  }

  const int nblk  = (E + 63) / 64;
  const int chunk = (nblk + 7) / 8;
  mp_main<<<chunk * 8, 256, 0, stream>>>(x, xb, use_xb, pos, sedge, rowp, colp,
                                         E, use_sort, chunk, b2x, W2p, b2p,
                                         wbuf, out_x, out_pos);
}

// Round 6
// 359.816 us; speedup vs baseline: 1.0102x; 1.0102x over previous
//
#include <hip/hip_runtime.h>

typedef short short8 __attribute__((ext_vector_type(8)));
typedef float floatx4 __attribute__((ext_vector_type(4)));

__device__ __forceinline__ unsigned short f2bf(float f) {
  unsigned int u = __float_as_uint(f);
  u += 0x7FFFu + ((u >> 16) & 1u);   // RNE
  return (unsigned short)(u >> 16);
}

#if __has_builtin(__builtin_amdgcn_cvt_pk_bf16_f32)
typedef __bf16 bf16x2_t __attribute__((ext_vector_type(2)));
__device__ __forceinline__ unsigned int pk2bf(float lo, float hi) {
  bf16x2_t v = __builtin_amdgcn_cvt_pk_bf16_f32(lo, hi);
  return __builtin_bit_cast(unsigned int, v);
}
#else
__device__ __forceinline__ unsigned int pk2bf(float lo, float hi) {
  return (unsigned)f2bf(lo) | ((unsigned)f2bf(hi) << 16);
}
#endif

// ---------------------------------------------------------------------------
// Fused setup: job0 zero d_out | job1 zero hist | job2 x->bf16 | job3 weight
// repack. K=128 fragments only (dist^2 row + bias handled in mp_main VALU).
// wbuf (ushort): [0,16384) W1x [nt=8][ks=4][lane=64][j=8]; [16384,32768) W1p;
// [32768,40960) W2x [nt=4][ks=4][lane=64][j=8].  val = W[k][n],
// k = ks*32+(lane>>4)*8+j, n = nt*16+(lane&15).
// ---------------------------------------------------------------------------
__global__ __launch_bounds__(256) void k_setup(
    float* __restrict__ out, int out_n,
    int* __restrict__ hist, int N,
    const float* __restrict__ x, unsigned short* __restrict__ xb, int nx,
    const float* __restrict__ W1x, const float* __restrict__ W1p,
    const float* __restrict__ W2x, unsigned short* __restrict__ wbuf,
    int b1, int b2, int b3)
{
  int blk = blockIdx.x, t = threadIdx.x;
  if (blk < b1) {                                   // job0: zero d_out
    int i = (blk * 256 + t) * 4;
    if (i + 4 <= out_n) {
      *(float4*)(out + i) = make_float4(0.f, 0.f, 0.f, 0.f);
    } else {
      for (int k = i; k < out_n; ++k) out[k] = 0.f;
    }
  } else if (blk < b2) {                            // job1: zero hist
    int i = (blk - b1) * 256 + t;
    if (i < N) hist[i] = 0;
  } else if (blk < b3) {                            // job2: x -> bf16
    int i = ((blk - b2) * 256 + t) * 8;
    if (i < nx) {
      float4 a = *(const float4*)(x + i);
      float4 b = *(const float4*)(x + i + 4);
      uint4 o;
      o.x = pk2bf(a.x, a.y); o.y = pk2bf(a.z, a.w);
      o.z = pk2bf(b.x, b.y); o.w = pk2bf(b.z, b.w);
      *(uint4*)(xb + i) = o;
    }
  } else {                                          // job3: weight repack
    int i = (blk - b3) * 256 + t;
    if (i >= 40960) return;
    int jj = i & 7, lane = (i >> 3) & 63, ks = (i >> 9) & 3;
    int k = ks*32 + (lane >> 4)*8 + jj;
    float v;
    if (i < 32768) {
      const float* W = (i < 16384) ? W1x : W1p;
      int nt = (i >> 11) & 7;
      v = W[k*128 + nt*16 + (lane & 15)];
    } else {
      int nt = (i >> 11) & 3;
      v = W2x[k*64 + nt*16 + (lane & 15)];
    }
    wbuf[i] = f2bf(v);
  }
}

// ---------------------------------------------------------------------------
// Counting sort by destination (col): hist -> scan -> scatter.
// ---------------------------------------------------------------------------
__global__ void k_hist(const int* __restrict__ col, int E, int* __restrict__ hist) {
  int i = blockIdx.x * 256 + threadIdx.x;
  if (i < E) atomicAdd(&hist[col[i]], 1);
}

__global__ __launch_bounds__(256) void k_scan_a(const int* __restrict__ hist, int N,
                                                int* __restrict__ excl, int* __restrict__ bsum) {
  __shared__ int wtot[4], wexc[4];
  int t = threadIdx.x, lane = t & 63, w = t >> 6;
  int base = blockIdx.x * 1024 + t * 4;
  int v0 = (base + 0 < N) ? hist[base + 0] : 0;
  int v1 = (base + 1 < N) ? hist[base + 1] : 0;
  int v2 = (base + 2 < N) ? hist[base + 2] : 0;
  int v3 = (base + 3 < N) ? hist[base + 3] : 0;
  int T = v0 + v1 + v2 + v3;
  int inc = T;
  #pragma unroll
  for (int s = 1; s < 64; s <<= 1) {
    int u = __shfl_up(inc, s, 64);
    if (lane >= s) inc += u;
  }
  if (lane == 63) wtot[w] = inc;
  __syncthreads();
  if (t == 0) {
    int a = 0;
    #pragma unroll
    for (int i = 0; i < 4; ++i) { wexc[i] = a; a += wtot[i]; }
    bsum[blockIdx.x] = a;
  }
  __syncthreads();
  int tex = wexc[w] + (inc - T);
  if (base + 0 < N) excl[base + 0] = tex;
  if (base + 1 < N) excl[base + 1] = tex + v0;
  if (base + 2 < N) excl[base + 2] = tex + v0 + v1;
  if (base + 3 < N) excl[base + 3] = tex + v0 + v1 + v2;
}

// scatter with inlined top-level scan of per-scan_a-block sums (NB <= 64)
__global__ __launch_bounds__(256) void k_scatter(
    const int* __restrict__ row, const int* __restrict__ col, int E,
    int* __restrict__ excl, const int* __restrict__ bsum, int NB,
    int2* __restrict__ sedge) {
  __shared__ int boff_sh[64];
  int t = threadIdx.x;
  if (t < 64) {
    int v = (t < NB) ? bsum[t] : 0;
    int inc = v;
    #pragma unroll
    for (int s = 1; s < 64; s <<= 1) {
      int u = __shfl_up(inc, s, 64);
      if (t >= s) inc += u;
    }
    boff_sh[t] = inc - v;
  }
  __syncthreads();
  int i = blockIdx.x * 256 + t;
  if (i < E) {
    int c = col[i];
    int p = atomicAdd(&excl[c], 1) + boff_sh[c >> 10];
    sedge[p] = make_int2(row[i], c);
  }
}

// ---------------------------------------------------------------------------
// Main fused kernel: 64 sorted edges/block, 512 threads (8 waves).
// Wave w owns h-tile w in GEMM1 (K=128, 4 MFMA ks); dist^2 row + bias added
// in fp32 VALU epilogue (more accurate than the old K=160 bf16 fold, and
// saves LDS + fragments). Wave pairs {w, w+4} split et-windows in GEMM2.
// 2 barriers/block. Segmented suffix-sum epilogue over sorted cols (R2).
// LDS 38144 B -> 4 blocks/CU; 8 waves/block doubles resident waves vs R4.
// ---------------------------------------------------------------------------
__global__ __launch_bounds__(512) void mp_main(
    const float* __restrict__ x, const unsigned short* __restrict__ xb, int use_xb,
    const float* __restrict__ pos,
    const int2* __restrict__ sedge,
    const int* __restrict__ rowp, const int* __restrict__ colp,
    int E, int sorted,
    const float* __restrict__ W1x, const float* __restrict__ b1x,
    const float* __restrict__ W1p, const float* __restrict__ b1p,
    const float* __restrict__ b2x, const float* __restrict__ W2p,
    const float* __restrict__ b2p,
    const unsigned short* __restrict__ wbuf,
    float* __restrict__ out_x, float* __restrict__ out_pos)
{
  __shared__ __align__(16) unsigned short C_lds[64][136];  // 17408 B
  __shared__ __align__(16) unsigned short H_lds[64][136];  // 17408 B
  __shared__ float dsq_sh[64];
  __shared__ float rel_lds[64][3];
  __shared__ int   col_sh[64];
  __shared__ float wsum[8][64];

  const int t    = threadIdx.x;
  const int e0   = blockIdx.x * 64;
  const int wv   = t >> 6;        // 0..7
  const int lane = t & 63;
  const int quad = lane >> 4;
  const int lc   = lane & 15;

  // ---- phase 1: per-edge scalars + combined-feature staging (bf16) ----
  if (t < 64) {
    int e = e0 + t;
    float rp0 = 0.f, rp1 = 0.f, rp2 = 0.f, dsq = 0.f; int c = -1;
    if (e < E) {
      int r;
      if (sorted) { int2 rc = sedge[e]; r = rc.x; c = rc.y; }
      else        { r = rowp[e]; c = colp[e]; }
      float pr0 = pos[r*3+0], pr1 = pos[r*3+1], pr2 = pos[r*3+2];
      float pc0 = pos[c*3+0], pc1 = pos[c*3+1], pc2 = pos[c*3+2];
      rp0 = pr0 - pc0; rp1 = pr1 - pc1; rp2 = pr2 - pc2;
      dsq = rp0*rp0 + rp1*rp1 + rp2*rp2;
    }
    rel_lds[t][0] = rp0; rel_lds[t][1] = rp1; rel_lds[t][2] = rp2;
    col_sh[t] = c;
    dsq_sh[t] = dsq;
  }
  {
    const int s = t >> 3, p = t & 7;     // 8 threads/edge, 8 feats per side
    const int e = e0 + s;
    uint4 rv, cv;
    if (e < E) {
      int r, c;
      if (sorted) { int2 rc = sedge[e]; r = rc.x; c = rc.y; }
      else        { r = rowp[e]; c = colp[e]; }
      if (use_xb) {
        rv = *(const uint4*)(xb + (size_t)r*64 + p*8);
        cv = *(const uint4*)(xb + (size_t)c*64 + p*8);
      } else {
        const float4* xr = (const float4*)(x + (size_t)r*64 + p*8);
        const float4* xc = (const float4*)(x + (size_t)c*64 + p*8);
        float4 a0 = xr[0], a1 = xr[1];
        float4 d0 = xc[0], d1 = xc[1];
        rv = make_uint4(pk2bf(a0.x,a0.y), pk2bf(a0.z,a0.w), pk2bf(a1.x,a1.y), pk2bf(a1.z,a1.w));
        cv = make_uint4(pk2bf(d0.x,d0.y), pk2bf(d0.z,d0.w), pk2bf(d1.x,d1.y), pk2bf(d1.z,d1.w));
      }
    } else {
      rv = cv = make_uint4(0u, 0u, 0u, 0u);
    }
    *(uint4*)&C_lds[s][p*8]      = rv;
    *(uint4*)&C_lds[s][64 + p*8] = cv;
  }

  // ---- per-wave weight fragments + scalar rows (no LDS dependence) ----
  const short8* __restrict__ w1x_f = (const short8*)(wbuf);
  const short8* __restrict__ w1p_f = (const short8*)(wbuf + 16384);
  const short8* __restrict__ w2x_f = (const short8*)(wbuf + 32768);

  const int ht = wv;          // GEMM1 h-tile
  const int ft = wv & 3;      // GEMM2 f-tile
  short8 a1x[4], a1p[4], a2w[4];
  #pragma unroll
  for (int ks = 0; ks < 4; ++ks) {
    a1x[ks] = w1x_f[(ht*4 + ks)*64 + lane];
    a1p[ks] = w1p_f[(ht*4 + ks)*64 + lane];
    a2w[ks] = w2x_f[(ft*4 + ks)*64 + lane];
  }
  const int hidx = ht*16 + quad*4;
  const int fidx = ft*16 + quad*4;
  float w128x[4], b1xv[4], w128p[4], b1pv[4], wp2v[4], b2xr[4];
  #pragma unroll
  for (int r = 0; r < 4; ++r) {
    w128x[r] = W1x[16384 + hidx + r];   // dist^2 row (row 128 of [129][128])
    b1xv[r]  = b1x[hidx + r];
    w128p[r] = W1p[16384 + hidx + r];
    b1pv[r]  = b1p[hidx + r];
    wp2v[r]  = W2p[hidx + r];
    b2xr[r]  = b2x[fidx + r];
  }
  const float b2ps = b2p[0];
  __syncthreads();

  // ---- GEMM1: wave's h-tile over all 4 et-windows; silu; H^T -> LDS ----
  #pragma unroll 1
  for (int et = 0; et < 4; ++et) {
    floatx4 ax = {0,0,0,0}, ap = {0,0,0,0};
    #pragma unroll
    for (int ks = 0; ks < 4; ++ks) {
      short8 b = *(const short8*)&C_lds[et*16 + lc][ks*32 + quad*8];
      ax = __builtin_amdgcn_mfma_f32_16x16x32_bf16(a1x[ks], b, ax, 0, 0, 0);
      ap = __builtin_amdgcn_mfma_f32_16x16x32_bf16(a1p[ks], b, ap, 0, 0, 0);
    }
    const float dsqv = dsq_sh[et*16 + lc];
    float ps = 0.f, sx[4];
    #pragma unroll
    for (int r = 0; r < 4; ++r) {
      float hx = ax[r] + dsqv*w128x[r] + b1xv[r];
      sx[r] = hx * __builtin_amdgcn_rcpf(1.f + __expf(-hx));
      float hp = ap[r] + dsqv*w128p[r] + b1pv[r];
      float sp = hp * __builtin_amdgcn_rcpf(1.f + __expf(-hp));
      ps += sp * wp2v[r];
    }
    *(uint2*)&H_lds[et*16 + lc][ht*16 + quad*4] =
        make_uint2(pk2bf(sx[0], sx[1]), pk2bf(sx[2], sx[3]));
    ps += __shfl_xor(ps, 16, 64);
    ps += __shfl_xor(ps, 32, 64);
    if (lane < 16) wsum[wv][et*16 + lane] = ps;
  }
  __syncthreads();

  // ---- GEMM2: wave pair splits et-windows; segmented scatter ----
  const int etb = (wv >> 2) * 2;
  #pragma unroll
  for (int eti = 0; eti < 2; ++eti) {
    const int et = etb + eti;
    floatx4 acc = {0,0,0,0};
    #pragma unroll
    for (int ks = 0; ks < 4; ++ks) {
      short8 b = *(const short8*)&H_lds[et*16 + lc][ks*32 + quad*8];
      acc = __builtin_amdgcn_mfma_f32_16x16x32_bf16(a2w[ks], b, acc, 0, 0, 0);
    }
    int edge = et*16 + lc;
    int myc = col_sh[edge];
    float v0 = acc[0] + b2xr[0], v1 = acc[1] + b2xr[1];
    float v2 = acc[2] + b2xr[2], v3 = acc[3] + b2xr[3];
    if (sorted) {
      #pragma unroll
      for (int s = 1; s < 16; s <<= 1) {
        int   nc  = __shfl_down(myc, s, 64);
        float n0  = __shfl_down(v0,  s, 64);
        float n1  = __shfl_down(v1,  s, 64);
        float n2  = __shfl_down(v2,  s, 64);
        float n3  = __shfl_down(v3,  s, 64);
        if ((lc + s < 16) && (nc == myc)) { v0 += n0; v1 += n1; v2 += n2; v3 += n3; }
      }
    }
    bool head = (myc >= 0) && (!sorted || lc == 0 || col_sh[edge-1] != myc);
    if (head) {
      float* dst = out_x + (size_t)myc*64 + ft*16 + quad*4;
      atomicAdd(dst + 0, v0);
      atomicAdd(dst + 1, v1);
      atomicAdd(dst + 2, v2);
      atomicAdd(dst + 3, v3);
    }
  }

  // ---- phi_p epilogue: weight * rel_pos, segmented over 64 sorted edges ----
  if (t < 64) {
    int c = col_sh[t];
    float w = wsum[0][t] + wsum[1][t] + wsum[2][t] + wsum[3][t]
            + wsum[4][t] + wsum[5][t] + wsum[6][t] + wsum[7][t] + b2ps;
    float p0 = w * rel_lds[t][0], p1 = w * rel_lds[t][1], p2 = w * rel_lds[t][2];
    if (sorted) {
      #pragma unroll
      for (int s = 1; s < 64; s <<= 1) {
        int   nc = __shfl_down(c,  s, 64);
        float n0 = __shfl_down(p0, s, 64);
        float n1 = __shfl_down(p1, s, 64);
        float n2 = __shfl_down(p2, s, 64);
        if ((t + s < 64) && (nc == c)) { p0 += n0; p1 += n1; p2 += n2; }
      }
    }
    bool head = (c >= 0) && (!sorted || t == 0 || col_sh[t-1] != c);
    if (head) {
      atomicAdd(&out_pos[(size_t)c*3 + 0], p0);
      atomicAdd(&out_pos[(size_t)c*3 + 1], p1);
      atomicAdd(&out_pos[(size_t)c*3 + 2], p2);
    }
  }
}

extern "C" void kernel_launch(void* const* d_in, const int* in_sizes, int n_in,
                              void* d_out, int out_size, void* d_ws, size_t ws_size,
                              hipStream_t stream) {
  const float* x   = (const float*)d_in[0];
  const float* pos = (const float*)d_in[1];
  const int*   ei  = (const int*)d_in[2];
  const float* W1x = (const float*)d_in[3];
  const float* b1x = (const float*)d_in[4];
  const float* W2x = (const float*)d_in[5];
  const float* b2x = (const float*)d_in[6];
  const float* W1p = (const float*)d_in[7];
  const float* b1p = (const float*)d_in[8];
  const float* W2p = (const float*)d_in[9];
  const float* b2p = (const float*)d_in[10];

  const int E = in_sizes[2] / 2;        // 800000
  const int N = in_sizes[0] / 64;       // 50000
  const int* rowp = ei;
  const int* colp = ei + E;
  float* out_x   = (float*)d_out;
  float* out_pos = out_x + (size_t)N * 64;

  char* ws = (char*)d_ws;
  const size_t xb_bytes = (size_t)N * 64 * 2;        // 6,400,000
  size_t base = 0;
  int use_xb = 0;
  {
    size_t needA = xb_bytes + 81920 + 200192 + 512 + (size_t)E * 8;
    if (ws_size >= needA) { use_xb = 1; base = xb_bytes; }
  }
  unsigned short* xb   = (unsigned short*)ws;
  unsigned short* wbuf = (unsigned short*)(ws + base);
  int*  off   = (int*)(ws + base + 81920);
  int*  bsum  = (int*)(ws + base + 81920 + 200192);
  int2* sedge = (int2*)(ws + base + 81920 + 200192 + 512);
  const size_t need_sort = base + 81920 + 200192 + 512 + (size_t)E * 8;
  const int use_sort = (ws_size >= need_sort) ? 1 : 0;

  // fused setup dispatch
  const int nx = N * 64;
  const int nb_out  = (out_size + 1023) / 1024;          // 4 floats/thread
  const int nb_hist = use_sort ? (N + 255) / 256 : 0;
  const int nb_xcvt = use_xb ? (nx + 2047) / 2048 : 0;   // 8 elems/thread
  const int nb_prep = 160;                               // 40960 frags
  const int b1 = nb_out, b2 = b1 + nb_hist, b3 = b2 + nb_xcvt;
  const int setup_blocks = b3 + nb_prep;
  k_setup<<<setup_blocks, 256, 0, stream>>>(
      (float*)d_out, out_size, off, N, x, xb, nx,
      W1x, W1p, W2x, wbuf, b1, b2, b3);

  if (use_sort) {
    const int NB = (N + 1023) / 1024;   // 49 (<=64)
    k_hist<<<(E + 255) / 256, 256, 0, stream>>>(colp, E, off);
    k_scan_a<<<NB, 256, 0, stream>>>(off, N, off, bsum);
    k_scatter<<<(E + 255) / 256, 256, 0, stream>>>(rowp, colp, E, off, bsum, NB, sedge);
  }

  mp_main<<<(E + 63) / 64, 512, 0, stream>>>(x, xb, use_xb, pos, sedge, rowp, colp,
                                             E, use_sort,
                                             W1x, b1x, W1p, b1p, b2x, W2p, b2p,
                                             wbuf, out_x, out_pos);
}

// Round 7
// 318.577 us; speedup vs baseline: 1.1410x; 1.1294x over previous
//
#include <hip/hip_runtime.h>

typedef short short8 __attribute__((ext_vector_type(8)));
typedef float floatx4 __attribute__((ext_vector_type(4)));

__device__ __forceinline__ unsigned short f2bf(float f) {
  unsigned int u = __float_as_uint(f);
  u += 0x7FFFu + ((u >> 16) & 1u);   // RNE
  return (unsigned short)(u >> 16);
}

#if __has_builtin(__builtin_amdgcn_cvt_pk_bf16_f32)
typedef __bf16 bf16x2_t __attribute__((ext_vector_type(2)));
__device__ __forceinline__ unsigned int pk2bf(float lo, float hi) {
  bf16x2_t v = __builtin_amdgcn_cvt_pk_bf16_f32(lo, hi);
  return __builtin_bit_cast(unsigned int, v);
}
#else
__device__ __forceinline__ unsigned int pk2bf(float lo, float hi) {
  return (unsigned)f2bf(lo) | ((unsigned)f2bf(hi) << 16);
}
#endif

__device__ __forceinline__ float silu(float h) {
  return h * __builtin_amdgcn_rcpf(1.f + __expf(-h));
}

// ---------------------------------------------------------------------------
// Fused setup: job0 zero d_out | job1 col histogram (int4, 4 edges/thread;
// `off` pre-zeroed by hipMemsetAsync) | job2 weight repack.
// wbuf (ushort): [0,16384) W1x [nt=8][ks=4][lane=64][j=8]; [16384,32768) W1p;
// [32768,40960) W2x [nt=4][ks=4][lane=64][j=8].  val = W[k][n],
// k = ks*32+(lane>>4)*8+j, n = nt*16+(lane&15).  (A- and B-operand layouts
// coincide positionally, so these serve either role.)
// ---------------------------------------------------------------------------
__global__ __launch_bounds__(256) void k_setup(
    float* __restrict__ out, int out_n,
    const int* __restrict__ colp, int E, int* __restrict__ hist,
    const float* __restrict__ W1x, const float* __restrict__ W1p,
    const float* __restrict__ W2x, unsigned short* __restrict__ wbuf,
    int b1, int b2)
{
  int blk = blockIdx.x, t = threadIdx.x;
  if (blk < b1) {                                   // job0: zero d_out
    int i = (blk * 256 + t) * 4;
    if (i + 4 <= out_n) {
      *(float4*)(out + i) = make_float4(0.f, 0.f, 0.f, 0.f);
    } else {
      for (int k = i; k < out_n; ++k) out[k] = 0.f;
    }
  } else if (blk < b2) {                            // job1: histogram
    int i = ((blk - b1) * 256 + t) * 4;
    if (i + 4 <= E) {
      int4 c = *(const int4*)(colp + i);
      atomicAdd(&hist[c.x], 1); atomicAdd(&hist[c.y], 1);
      atomicAdd(&hist[c.z], 1); atomicAdd(&hist[c.w], 1);
    } else {
      for (int k = i; k < E; ++k) atomicAdd(&hist[colp[k]], 1);
    }
  } else {                                          // job2: weight repack
    int i = (blk - b2) * 256 + t;
    if (i >= 40960) return;
    int jj = i & 7, lane = (i >> 3) & 63, ks = (i >> 9) & 3;
    int k = ks*32 + (lane >> 4)*8 + jj;
    float v;
    if (i < 32768) {
      const float* W = (i < 16384) ? W1x : W1p;
      int nt = (i >> 11) & 7;
      v = W[k*128 + nt*16 + (lane & 15)];
    } else {
      int nt = (i >> 11) & 3;
      v = W2x[k*64 + nt*16 + (lane & 15)];
    }
    wbuf[i] = f2bf(v);
  }
}

// ---------------------------------------------------------------------------
// Per-node layer-1 partials (the algorithmic core of R7):
//   Ar[n][h] = sum_{k<64} x[n][k] W1[k][h] + b1[h]      (row-side, bias folded)
//   Ac[n][h] = sum_{k<64} x[n][k] W1[64+k][h]           (col-side)
// for both MLPs, stored bf16 interleaved per h: uint[n*128+h] = (x | p<<16).
// 64 nodes/block, 256 threads (4 waves); wave wv owns h-tiles {wv, wv+4}.
// Stores are fully coalesced (16 lanes = 64 B line per quad-row).
// ---------------------------------------------------------------------------
__global__ __launch_bounds__(256) void k_nodeA(
    const float* __restrict__ x, const unsigned short* __restrict__ wbuf,
    const float* __restrict__ b1x, const float* __restrict__ b1p, int N,
    unsigned int* __restrict__ Ar, unsigned int* __restrict__ Ac)
{
  __shared__ __align__(16) unsigned short xt[64][72];
  const int t = threadIdx.x, n0 = blockIdx.x * 64;
  const int wv = t >> 6, lane = t & 63, quad = lane >> 4, lc = lane & 15;

  {  // stage x tile (bf16)
    int nd = t >> 2, p = t & 3;
    int n = n0 + nd;
    uint4 o0, o1;
    if (n < N) {
      const float4* xp = (const float4*)(x + (size_t)n*64 + p*16);
      float4 a = xp[0], b = xp[1], c = xp[2], d = xp[3];
      o0 = make_uint4(pk2bf(a.x,a.y), pk2bf(a.z,a.w), pk2bf(b.x,b.y), pk2bf(b.z,b.w));
      o1 = make_uint4(pk2bf(c.x,c.y), pk2bf(c.z,c.w), pk2bf(d.x,d.y), pk2bf(d.z,d.w));
    } else {
      o0 = o1 = make_uint4(0u,0u,0u,0u);
    }
    *(uint4*)&xt[nd][p*16]     = o0;
    *(uint4*)&xt[nd][p*16 + 8] = o1;
  }

  const short8* __restrict__ w1x_f = (const short8*)wbuf;
  const short8* __restrict__ w1p_f = (const short8*)(wbuf + 16384);
  short8 fxr[2][2], fxc[2][2], fpr[2][2], fpc[2][2];
  float bx[2], bp[2];
  #pragma unroll
  for (int ti = 0; ti < 2; ++ti) {
    int nt = wv + 4*ti;
    #pragma unroll
    for (int k2 = 0; k2 < 2; ++k2) {
      fxr[ti][k2] = w1x_f[(nt*4 + k2)*64 + lane];
      fxc[ti][k2] = w1x_f[(nt*4 + 2 + k2)*64 + lane];
      fpr[ti][k2] = w1p_f[(nt*4 + k2)*64 + lane];
      fpc[ti][k2] = w1p_f[(nt*4 + 2 + k2)*64 + lane];
    }
    bx[ti] = b1x[nt*16 + lc];
    bp[ti] = b1p[nt*16 + lc];
  }
  __syncthreads();

  #pragma unroll 1
  for (int mw = 0; mw < 4; ++mw) {
    short8 a0 = *(const short8*)&xt[mw*16 + lc][quad*8];       // k 0..31
    short8 a1 = *(const short8*)&xt[mw*16 + lc][32 + quad*8];  // k 32..63
    floatx4 xr[2], xc[2], pr[2], pc[2];
    #pragma unroll
    for (int ti = 0; ti < 2; ++ti) {
      xr[ti] = (floatx4){0,0,0,0}; xc[ti] = (floatx4){0,0,0,0};
      pr[ti] = (floatx4){0,0,0,0}; pc[ti] = (floatx4){0,0,0,0};
      xr[ti] = __builtin_amdgcn_mfma_f32_16x16x32_bf16(a0, fxr[ti][0], xr[ti], 0,0,0);
      xr[ti] = __builtin_amdgcn_mfma_f32_16x16x32_bf16(a1, fxr[ti][1], xr[ti], 0,0,0);
      xc[ti] = __builtin_amdgcn_mfma_f32_16x16x32_bf16(a0, fxc[ti][0], xc[ti], 0,0,0);
      xc[ti] = __builtin_amdgcn_mfma_f32_16x16x32_bf16(a1, fxc[ti][1], xc[ti], 0,0,0);
      pr[ti] = __builtin_amdgcn_mfma_f32_16x16x32_bf16(a0, fpr[ti][0], pr[ti], 0,0,0);
      pr[ti] = __builtin_amdgcn_mfma_f32_16x16x32_bf16(a1, fpr[ti][1], pr[ti], 0,0,0);
      pc[ti] = __builtin_amdgcn_mfma_f32_16x16x32_bf16(a0, fpc[ti][0], pc[ti], 0,0,0);
      pc[ti] = __builtin_amdgcn_mfma_f32_16x16x32_bf16(a1, fpc[ti][1], pc[ti], 0,0,0);
    }
    // D[m][n]: node = mw*16 + quad*4 + r, h = (wv+4*ti)*16 + lc
    #pragma unroll
    for (int ti = 0; ti < 2; ++ti) {
      int h = (wv + 4*ti)*16 + lc;
      #pragma unroll
      for (int rr = 0; rr < 4; ++rr) {
        int nd = n0 + mw*16 + quad*4 + rr;
        if (nd < N) {
          Ar[(size_t)nd*128 + h] = pk2bf(xr[ti][rr] + bx[ti], pr[ti][rr] + bp[ti]);
          Ac[(size_t)nd*128 + h] = pk2bf(xc[ti][rr], pc[ti][rr]);
        }
      }
    }
  }
}

// ---------------------------------------------------------------------------
// Counting sort by col: scan + scatter ( histogram done in k_setup ).
// ---------------------------------------------------------------------------
__global__ __launch_bounds__(256) void k_scan_a(const int* __restrict__ hist, int N,
                                                int* __restrict__ excl, int* __restrict__ bsum) {
  __shared__ int wtot[4], wexc[4];
  int t = threadIdx.x, lane = t & 63, w = t >> 6;
  int base = blockIdx.x * 1024 + t * 4;
  int v0 = (base + 0 < N) ? hist[base + 0] : 0;
  int v1 = (base + 1 < N) ? hist[base + 1] : 0;
  int v2 = (base + 2 < N) ? hist[base + 2] : 0;
  int v3 = (base + 3 < N) ? hist[base + 3] : 0;
  int T = v0 + v1 + v2 + v3;
  int inc = T;
  #pragma unroll
  for (int s = 1; s < 64; s <<= 1) {
    int u = __shfl_up(inc, s, 64);
    if (lane >= s) inc += u;
  }
  if (lane == 63) wtot[w] = inc;
  __syncthreads();
  if (t == 0) {
    int a = 0;
    #pragma unroll
    for (int i = 0; i < 4; ++i) { wexc[i] = a; a += wtot[i]; }
    bsum[blockIdx.x] = a;
  }
  __syncthreads();
  int tex = wexc[w] + (inc - T);
  if (base + 0 < N) excl[base + 0] = tex;
  if (base + 1 < N) excl[base + 1] = tex + v0;
  if (base + 2 < N) excl[base + 2] = tex + v0 + v1;
  if (base + 3 < N) excl[base + 3] = tex + v0 + v1 + v2;
}

__global__ __launch_bounds__(256) void k_scatter(
    const int* __restrict__ row, const int* __restrict__ col, int E,
    int* __restrict__ excl, const int* __restrict__ bsum, int NB,
    int2* __restrict__ sedge) {
  __shared__ int boff_sh[64];
  int t = threadIdx.x;
  if (t < 64) {
    int v = (t < NB) ? bsum[t] : 0;
    int inc = v;
    #pragma unroll
    for (int s = 1; s < 64; s <<= 1) {
      int u = __shfl_up(inc, s, 64);
      if (t >= s) inc += u;
    }
    boff_sh[t] = inc - v;
  }
  __syncthreads();
  int i = blockIdx.x * 256 + t;
  if (i < E) {
    int c = col[i];
    int p = atomicAdd(&excl[c], 1) + boff_sh[c >> 10];
    sedge[p] = make_int2(row[i], c);
  }
}

// ---------------------------------------------------------------------------
// Main kernel (table path): 64 sorted edges/block, 256 threads (4 waves).
// Layer 1 = per-lane table gathers: h = Ar[row] + Ac[col] + dsq*W1[128][h]
// (bias folded into Ar). No C_lds, no W1 fragments, no GEMM1 MFMAs.
// Layer 2 = MFMA (K=128) from H_lds, segmented suffix-sum scatter (R2).
// ---------------------------------------------------------------------------
__global__ __launch_bounds__(256) void mp_main(
    const float* __restrict__ pos,
    const int2* __restrict__ sedge,
    const int* __restrict__ rowp, const int* __restrict__ colp,
    int E, int sorted,
    const unsigned int* __restrict__ Ar, const unsigned int* __restrict__ Ac,
    const float* __restrict__ W1x, const float* __restrict__ W1p,
    const float* __restrict__ b2x, const float* __restrict__ W2p,
    const float* __restrict__ b2p,
    const unsigned short* __restrict__ wbuf,
    float* __restrict__ out_x, float* __restrict__ out_pos)
{
  __shared__ __align__(16) unsigned short H_lds[64][136];  // 17408 B
  __shared__ __align__(16) uint4 edata[64];                // {row, col, dsq, 0}
  __shared__ float rel_lds[64][3];
  __shared__ int   col_sh[64];
  __shared__ float wsum[4][64];

  const int t    = threadIdx.x;
  const int e0   = blockIdx.x * 64;
  const int wv   = t >> 6;
  const int lane = t & 63;
  const int quad = lane >> 4;
  const int lc   = lane & 15;

  // ---- phase 1: per-edge scalars ----
  if (t < 64) {
    int e = e0 + t;
    int r = 0, c = 0, cs = -1;
    float rp0 = 0.f, rp1 = 0.f, rp2 = 0.f, dsq = 0.f;
    if (e < E) {
      if (sorted) { int2 rc = sedge[e]; r = rc.x; c = rc.y; }
      else        { r = rowp[e]; c = colp[e]; }
      cs = c;
      float pr0 = pos[r*3+0], pr1 = pos[r*3+1], pr2 = pos[r*3+2];
      float pc0 = pos[c*3+0], pc1 = pos[c*3+1], pc2 = pos[c*3+2];
      rp0 = pr0 - pc0; rp1 = pr1 - pc1; rp2 = pr2 - pc2;
      dsq = rp0*rp0 + rp1*rp1 + rp2*rp2;
    }
    rel_lds[t][0] = rp0; rel_lds[t][1] = rp1; rel_lds[t][2] = rp2;
    col_sh[t] = cs;
    edata[t] = make_uint4((unsigned)r, (unsigned)c, __float_as_uint(dsq), 0u);
  }

  // ---- per-wave constants (no LDS dependence) ----
  const short8* __restrict__ w2x_f = (const short8*)(wbuf + 32768);
  short8 a2w[4];
  #pragma unroll
  for (int ks = 0; ks < 4; ++ks) a2w[ks] = w2x_f[(wv*4 + ks)*64 + lane];

  float w1xd[2][4], w1pd[2][4], wp2[2][4], b2xr[4];
  #pragma unroll
  for (int ti = 0; ti < 2; ++ti)
    #pragma unroll
    for (int r = 0; r < 4; ++r) {
      int h = (wv + 4*ti)*16 + quad*4 + r;
      w1xd[ti][r] = W1x[16384 + h];     // dist^2 row (row 128 of [129][128])
      w1pd[ti][r] = W1p[16384 + h];
      wp2[ti][r]  = W2p[h];
    }
  #pragma unroll
  for (int r = 0; r < 4; ++r) b2xr[r] = b2x[wv*16 + quad*4 + r];
  const float b2ps = b2p[0];
  __syncthreads();

  // ---- layer 1: table gather + silu; H^T -> LDS; phi_p dot ----
  #pragma unroll 2
  for (int et = 0; et < 4; ++et) {
    uint4 ed = edata[et*16 + lc];                  // broadcast across quads
    const float dsqv = __uint_as_float(ed.z);
    float ps = 0.f;
    #pragma unroll
    for (int ti = 0; ti < 2; ++ti) {
      const int ht = wv + 4*ti;
      const int hb = ht*32 + quad*8;               // ushort offset in node row
      uint4 va = *(const uint4*)((const unsigned short*)Ar + (size_t)ed.x*256 + hb);
      uint4 vc = *(const uint4*)((const unsigned short*)Ac + (size_t)ed.y*256 + hb);
      float sx[4];
      #pragma unroll
      for (int j = 0; j < 4; ++j) {
        unsigned a = (&va.x)[j], b = (&vc.x)[j];
        float hx = __uint_as_float(a << 16) + __uint_as_float(b << 16)
                 + dsqv * w1xd[ti][j];
        float hp = __uint_as_float(a & 0xffff0000u) + __uint_as_float(b & 0xffff0000u)
                 + dsqv * w1pd[ti][j];
        sx[j] = silu(hx);
        ps += silu(hp) * wp2[ti][j];
      }
      *(uint2*)&H_lds[et*16 + lc][ht*16 + quad*4] =
          make_uint2(pk2bf(sx[0], sx[1]), pk2bf(sx[2], sx[3]));
    }
    ps += __shfl_xor(ps, 16, 64);
    ps += __shfl_xor(ps, 32, 64);
    if (lane < 16) wsum[wv][et*16 + lane] = ps;
  }
  __syncthreads();

  // ---- layer 2: MSG^T = W2x^T @ H^T, segmented-reduce scatter ----
  #pragma unroll 2
  for (int et = 0; et < 4; ++et) {
    floatx4 acc = {0,0,0,0};
    #pragma unroll
    for (int ks = 0; ks < 4; ++ks) {
      short8 b = *(const short8*)&H_lds[et*16 + lc][ks*32 + quad*8];
      acc = __builtin_amdgcn_mfma_f32_16x16x32_bf16(a2w[ks], b, acc, 0, 0, 0);
    }
    int edge = et*16 + lc;
    int myc = col_sh[edge];
    float v0 = acc[0] + b2xr[0], v1 = acc[1] + b2xr[1];
    float v2 = acc[2] + b2xr[2], v3 = acc[3] + b2xr[3];
    if (sorted) {
      #pragma unroll
      for (int s = 1; s < 16; s <<= 1) {
        int   nc = __shfl_down(myc, s, 64);
        float n0 = __shfl_down(v0,  s, 64);
        float n1 = __shfl_down(v1,  s, 64);
        float n2 = __shfl_down(v2,  s, 64);
        float n3 = __shfl_down(v3,  s, 64);
        if ((lc + s < 16) && (nc == myc)) { v0 += n0; v1 += n1; v2 += n2; v3 += n3; }
      }
    }
    bool head = (myc >= 0) && (!sorted || lc == 0 || col_sh[edge-1] != myc);
    if (head) {
      float* dst = out_x + (size_t)myc*64 + wv*16 + quad*4;
      atomicAdd(dst + 0, v0);
      atomicAdd(dst + 1, v1);
      atomicAdd(dst + 2, v2);
      atomicAdd(dst + 3, v3);
    }
  }

  // ---- phi_p epilogue ----
  if (t < 64) {
    int c = col_sh[t];
    float w = wsum[0][t] + wsum[1][t] + wsum[2][t] + wsum[3][t] + b2ps;
    float p0 = w * rel_lds[t][0], p1 = w * rel_lds[t][1], p2 = w * rel_lds[t][2];
    if (sorted) {
      #pragma unroll
      for (int s = 1; s < 64; s <<= 1) {
        int   nc = __shfl_down(c,  s, 64);
        float n0 = __shfl_down(p0, s, 64);
        float n1 = __shfl_down(p1, s, 64);
        float n2 = __shfl_down(p2, s, 64);
        if ((t + s < 64) && (nc == c)) { p0 += n0; p1 += n1; p2 += n2; }
      }
    }
    bool head = (c >= 0) && (!sorted || t == 0 || col_sh[t-1] != c);
    if (head) {
      atomicAdd(&out_pos[(size_t)c*3 + 0], p0);
      atomicAdd(&out_pos[(size_t)c*3 + 1], p1);
      atomicAdd(&out_pos[(size_t)c*3 + 2], p2);
    }
  }
}

// ---------------------------------------------------------------------------
// Legacy fallback (R6 structure, x read directly as f32): used only if the
// workspace cannot hold the Ar/Ac tables.
// ---------------------------------------------------------------------------
__global__ __launch_bounds__(512) void mp_legacy(
    const float* __restrict__ x, const float* __restrict__ pos,
    const int2* __restrict__ sedge,
    const int* __restrict__ rowp, const int* __restrict__ colp,
    int E, int sorted,
    const float* __restrict__ W1x, const float* __restrict__ b1x,
    const float* __restrict__ W1p, const float* __restrict__ b1p,
    const float* __restrict__ b2x, const float* __restrict__ W2p,
    const float* __restrict__ b2p,
    const unsigned short* __restrict__ wbuf,
    float* __restrict__ out_x, float* __restrict__ out_pos)
{
  __shared__ __align__(16) unsigned short C_lds[64][136];
  __shared__ __align__(16) unsigned short H_lds[64][136];
  __shared__ float dsq_sh[64];
  __shared__ float rel_lds[64][3];
  __shared__ int   col_sh[64];
  __shared__ float wsum[8][64];

  const int t    = threadIdx.x;
  const int e0   = blockIdx.x * 64;
  const int wv   = t >> 6;
  const int lane = t & 63;
  const int quad = lane >> 4;
  const int lc   = lane & 15;

  if (t < 64) {
    int e = e0 + t;
    float rp0 = 0.f, rp1 = 0.f, rp2 = 0.f, dsq = 0.f; int c = -1;
    if (e < E) {
      int r;
      if (sorted) { int2 rc = sedge[e]; r = rc.x; c = rc.y; }
      else        { r = rowp[e]; c = colp[e]; }
      float pr0 = pos[r*3+0], pr1 = pos[r*3+1], pr2 = pos[r*3+2];
      float pc0 = pos[c*3+0], pc1 = pos[c*3+1], pc2 = pos[c*3+2];
      rp0 = pr0 - pc0; rp1 = pr1 - pc1; rp2 = pr2 - pc2;
      dsq = rp0*rp0 + rp1*rp1 + rp2*rp2;
    }
    rel_lds[t][0] = rp0; rel_lds[t][1] = rp1; rel_lds[t][2] = rp2;
    col_sh[t] = c;
    dsq_sh[t] = dsq;
  }
  {
    const int s = t >> 3, p = t & 7;
    const int e = e0 + s;
    uint4 rv, cv;
    if (e < E) {
      int r, c;
      if (sorted) { int2 rc = sedge[e]; r = rc.x; c = rc.y; }
      else        { r = rowp[e]; c = colp[e]; }
      const float4* xr = (const float4*)(x + (size_t)r*64 + p*8);
      const float4* xc = (const float4*)(x + (size_t)c*64 + p*8);
      float4 a0 = xr[0], a1 = xr[1];
      float4 d0 = xc[0], d1 = xc[1];
      rv = make_uint4(pk2bf(a0.x,a0.y), pk2bf(a0.z,a0.w), pk2bf(a1.x,a1.y), pk2bf(a1.z,a1.w));
      cv = make_uint4(pk2bf(d0.x,d0.y), pk2bf(d0.z,d0.w), pk2bf(d1.x,d1.y), pk2bf(d1.z,d1.w));
    } else {
      rv = cv = make_uint4(0u, 0u, 0u, 0u);
    }
    *(uint4*)&C_lds[s][p*8]      = rv;
    *(uint4*)&C_lds[s][64 + p*8] = cv;
  }

  const short8* __restrict__ w1x_f = (const short8*)(wbuf);
  const short8* __restrict__ w1p_f = (const short8*)(wbuf + 16384);
  const short8* __restrict__ w2x_f = (const short8*)(wbuf + 32768);

  const int ht = wv;
  const int ft = wv & 3;
  short8 a1x[4], a1p[4], a2w[4];
  #pragma unroll
  for (int ks = 0; ks < 4; ++ks) {
    a1x[ks] = w1x_f[(ht*4 + ks)*64 + lane];
    a1p[ks] = w1p_f[(ht*4 + ks)*64 + lane];
    a2w[ks] = w2x_f[(ft*4 + ks)*64 + lane];
  }
  const int hidx = ht*16 + quad*4;
  const int fidx = ft*16 + quad*4;
  float w128x[4], b1xv[4], w128p[4], b1pv[4], wp2v[4], b2xr[4];
  #pragma unroll
  for (int r = 0; r < 4; ++r) {
    w128x[r] = W1x[16384 + hidx + r];
    b1xv[r]  = b1x[hidx + r];
    w128p[r] = W1p[16384 + hidx + r];
    b1pv[r]  = b1p[hidx + r];
    wp2v[r]  = W2p[hidx + r];
    b2xr[r]  = b2x[fidx + r];
  }
  const float b2ps = b2p[0];
  __syncthreads();

  #pragma unroll 1
  for (int et = 0; et < 4; ++et) {
    floatx4 ax = {0,0,0,0}, ap = {0,0,0,0};
    #pragma unroll
    for (int ks = 0; ks < 4; ++ks) {
      short8 b = *(const short8*)&C_lds[et*16 + lc][ks*32 + quad*8];
      ax = __builtin_amdgcn_mfma_f32_16x16x32_bf16(a1x[ks], b, ax, 0, 0, 0);
      ap = __builtin_amdgcn_mfma_f32_16x16x32_bf16(a1p[ks], b, ap, 0, 0, 0);
    }
    const float dsqv = dsq_sh[et*16 + lc];
    float ps = 0.f, sx[4];
    #pragma unroll
    for (int r = 0; r < 4; ++r) {
      float hx = ax[r] + dsqv*w128x[r] + b1xv[r];
      sx[r] = silu(hx);
      float hp = ap[r] + dsqv*w128p[r] + b1pv[r];
      ps += silu(hp) * wp2v[r];
    }
    *(uint2*)&H_lds[et*16 + lc][ht*16 + quad*4] =
        make_uint2(pk2bf(sx[0], sx[1]), pk2bf(sx[2], sx[3]));
    ps += __shfl_xor(ps, 16, 64);
    ps += __shfl_xor(ps, 32, 64);
    if (lane < 16) wsum[wv][et*16 + lane] = ps;
  }
  __syncthreads();

  const int etb = (wv >> 2) * 2;
  #pragma unroll
  for (int eti = 0; eti < 2; ++eti) {
    const int et = etb + eti;
    floatx4 acc = {0,0,0,0};
    #pragma unroll
    for (int ks = 0; ks < 4; ++ks) {
      short8 b = *(const short8*)&H_lds[et*16 + lc][ks*32 + quad*8];
      acc = __builtin_amdgcn_mfma_f32_16x16x32_bf16(a2w[ks], b, acc, 0, 0, 0);
    }
    int edge = et*16 + lc;
    int myc = col_sh[edge];
    float v0 = acc[0] + b2xr[0], v1 = acc[1] + b2xr[1];
    float v2 = acc[2] + b2xr[2], v3 = acc[3] + b2xr[3];
    if (sorted) {
      #pragma unroll
      for (int s = 1; s < 16; s <<= 1) {
        int   nc = __shfl_down(myc, s, 64);
        float n0 = __shfl_down(v0,  s, 64);
        float n1 = __shfl_down(v1,  s, 64);
        float n2 = __shfl_down(v2,  s, 64);
        float n3 = __shfl_down(v3,  s, 64);
        if ((lc + s < 16) && (nc == myc)) { v0 += n0; v1 += n1; v2 += n2; v3 += n3; }
      }
    }
    bool head = (myc >= 0) && (!sorted || lc == 0 || col_sh[edge-1] != myc);
    if (head) {
      float* dst = out_x + (size_t)myc*64 + ft*16 + quad*4;
      atomicAdd(dst + 0, v0);
      atomicAdd(dst + 1, v1);
      atomicAdd(dst + 2, v2);
      atomicAdd(dst + 3, v3);
    }
  }

  if (t < 64) {
    int c = col_sh[t];
    float w = wsum[0][t] + wsum[1][t] + wsum[2][t] + wsum[3][t]
            + wsum[4][t] + wsum[5][t] + wsum[6][t] + wsum[7][t] + b2ps;
    float p0 = w * rel_lds[t][0], p1 = w * rel_lds[t][1], p2 = w * rel_lds[t][2];
    if (sorted) {
      #pragma unroll
      for (int s = 1; s < 64; s <<= 1) {
        int   nc = __shfl_down(c,  s, 64);
        float n0 = __shfl_down(p0, s, 64);
        float n1 = __shfl_down(p1, s, 64);
        float n2 = __shfl_down(p2, s, 64);
        if ((t + s < 64) && (nc == c)) { p0 += n0; p1 += n1; p2 += n2; }
      }
    }
    bool head = (c >= 0) && (!sorted || t == 0 || col_sh[t-1] != c);
    if (head) {
      atomicAdd(&out_pos[(size_t)c*3 + 0], p0);
      atomicAdd(&out_pos[(size_t)c*3 + 1], p1);
      atomicAdd(&out_pos[(size_t)c*3 + 2], p2);
    }
  }
}

extern "C" void kernel_launch(void* const* d_in, const int* in_sizes, int n_in,
                              void* d_out, int out_size, void* d_ws, size_t ws_size,
                              hipStream_t stream) {
  const float* x   = (const float*)d_in[0];
  const float* pos = (const float*)d_in[1];
  const int*   ei  = (const int*)d_in[2];
  const float* W1x = (const float*)d_in[3];
  const float* b1x = (const float*)d_in[4];
  const float* W2x = (const float*)d_in[5];
  const float* b2x = (const float*)d_in[6];
  const float* W1p = (const float*)d_in[7];
  const float* b1p = (const float*)d_in[8];
  const float* W2p = (const float*)d_in[9];
  const float* b2p = (const float*)d_in[10];

  const int E = in_sizes[2] / 2;        // 800000
  const int N = in_sizes[0] / 64;       // 50000
  const int* rowp = ei;
  const int* colp = ei + E;
  float* out_x   = (float*)d_out;
  float* out_pos = out_x + (size_t)N * 64;

  // ws layout: [Ar][Ac][wbuf][off][bsum][sedge] (tables optional)
  const size_t tab_one  = (size_t)N * 512;            // bytes per table (pad-free)
  const size_t tab_sz   = 2 * tab_one;                // 51.2 MB
  const size_t rest_sz  = 81920 + 200192 + 512 + (size_t)E * 8;
  const int use_tab  = (ws_size >= tab_sz + rest_sz) ? 1 : 0;
  const size_t base  = use_tab ? tab_sz : 0;
  const int use_sort = (ws_size >= base + rest_sz) ? 1 : 0;

  char* ws = (char*)d_ws;
  unsigned int*   Ar   = (unsigned int*)ws;
  unsigned int*   Ac   = (unsigned int*)(ws + tab_one);
  unsigned short* wbuf = (unsigned short*)(ws + base);
  int*  off   = (int*)(ws + base + 81920);
  int*  bsum  = (int*)(ws + base + 81920 + 200192);
  int2* sedge = (int2*)(ws + base + 81920 + 200192 + 512);

  if (use_sort) hipMemsetAsync(off, 0, (size_t)N * sizeof(int), stream);

  // fused setup: zero out | histogram | weight repack
  const int nb_out  = (out_size + 1023) / 1024;
  const int nb_hist = use_sort ? (E/4 + 255) / 256 + 1 : 0;
  const int nb_prep = 160;
  const int b1 = nb_out, b2 = b1 + nb_hist;
  k_setup<<<b2 + nb_prep, 256, 0, stream>>>(
      (float*)d_out, out_size, colp, use_sort ? E : 0, off,
      W1x, W1p, W2x, wbuf, b1, b2);

  if (use_tab)
    k_nodeA<<<(N + 63) / 64, 256, 0, stream>>>(x, wbuf, b1x, b1p, N, Ar, Ac);

  if (use_sort) {
    const int NB = (N + 1023) / 1024;   // 49 (<=64)
    k_scan_a<<<NB, 256, 0, stream>>>(off, N, off, bsum);
    k_scatter<<<(E + 255) / 256, 256, 0, stream>>>(rowp, colp, E, off, bsum, NB, sedge);
  }

  if (use_tab) {
    mp_main<<<(E + 63) / 64, 256, 0, stream>>>(
        pos, sedge, rowp, colp, E, use_sort,
        Ar, Ac, W1x, W1p, b2x, W2p, b2p, wbuf, out_x, out_pos);
  } else {
    mp_legacy<<<(E + 63) / 64, 512, 0, stream>>>(
        x, pos, sedge, rowp, colp, E, use_sort,
        W1x, b1x, W1p, b1p, b2x, W2p, b2p, wbuf, out_x, out_pos);
  }
}